// Round 1
// baseline (6096.695 us; speedup 1.0000x reference)
//
#include <hip/hip_runtime.h>

#define B_    4
#define N_    8192
#define CIN   128
#define COUT  256
#define M_    2048
#define K_    16
#define DM    64
#define MAXNN 64
#define CAP   128
#define R2    0.01f
#define EXT   0.1f

// Exact-rounded squared distance matching numpy's op order: (dx*dx + dy*dy) + dz*dz
__device__ __forceinline__ float d2_exact(float ax, float ay, float az,
                                          float bx, float by, float bz) {
    float dx = ax - bx, dy = ay - by, dz = az - bz;
    return __fadd_rn(__fadd_rn(__fmul_rn(dx, dx), __fmul_rn(dy, dy)), __fmul_rn(dz, dz));
}

// ---------------- K1: farthest point sampling (one block per cloud) ----------------
__global__ __launch_bounds__(1024) void fps_kernel(const float* __restrict__ pos,
                                                   int* __restrict__ idx_out,
                                                   float* __restrict__ out_pos) {
    const int b = blockIdx.x;
    const int t = threadIdx.x;
    const float* pb = pos + (size_t)b * N_ * 3;

    __shared__ float wval[16], wx[16], wy[16], wz[16];
    __shared__ int   widx[16];
    __shared__ float bc[3];

    float px[8], py[8], pz[8], mind[8];
#pragma unroll
    for (int j = 0; j < 8; j++) {
        int n = t + j * 1024;
        px[j] = pb[n * 3 + 0];
        py[j] = pb[n * 3 + 1];
        pz[j] = pb[n * 3 + 2];
    }
    float cx = pb[0], cy = pb[1], cz = pb[2];
#pragma unroll
    for (int j = 0; j < 8; j++) mind[j] = d2_exact(px[j], py[j], pz[j], cx, cy, cz);

    if (t == 0) {
        idx_out[b * M_ + 0] = 0;
        float* op = out_pos + ((size_t)(b * M_ + 0)) * 3;
        op[0] = cx; op[1] = cy; op[2] = cz;
    }

    for (int m = 1; m < M_; m++) {
        // local argmax over 8 register-resident candidates (ascending n => first-max)
        float bv = mind[0]; int bn = t; float bx = px[0], by = py[0], bz = pz[0];
#pragma unroll
        for (int j = 1; j < 8; j++) {
            if (mind[j] > bv) { bv = mind[j]; bn = t + j * 1024; bx = px[j]; by = py[j]; bz = pz[j]; }
        }
        // wave64 butterfly carrying (val, idx, pos); tie -> smaller global index
#pragma unroll
        for (int off = 1; off < 64; off <<= 1) {
            float ov = __shfl_xor(bv, off);
            int   on = __shfl_xor(bn, off);
            float ox = __shfl_xor(bx, off);
            float oy = __shfl_xor(by, off);
            float oz = __shfl_xor(bz, off);
            if (ov > bv || (ov == bv && on < bn)) { bv = ov; bn = on; bx = ox; by = oy; bz = oz; }
        }
        int wave = t >> 6;
        if ((t & 63) == 0) { wval[wave] = bv; widx[wave] = bn; wx[wave] = bx; wy[wave] = by; wz[wave] = bz; }
        __syncthreads();
        if (t == 0) {
            float Bv = wval[0]; int Bn = widx[0]; float Bx = wx[0], By = wy[0], Bz = wz[0];
#pragma unroll
            for (int w = 1; w < 16; w++) {
                float v = wval[w]; int n2 = widx[w];
                if (v > Bv || (v == Bv && n2 < Bn)) { Bv = v; Bn = n2; Bx = wx[w]; By = wy[w]; Bz = wz[w]; }
            }
            bc[0] = Bx; bc[1] = By; bc[2] = Bz;
            idx_out[b * M_ + m] = Bn;
            float* op = out_pos + ((size_t)(b * M_ + m)) * 3;
            op[0] = Bx; op[1] = By; op[2] = Bz;
        }
        __syncthreads();
        cx = bc[0]; cy = bc[1]; cz = bc[2];
#pragma unroll
        for (int j = 0; j < 8; j++) {
            float d = d2_exact(px[j], py[j], pz[j], cx, cy, cz);
            mind[j] = fminf(mind[j], d);
        }
    }
}

// ---------------- K2: pre-MLP  x_pre = x @ W_pre + b_pre ----------------
__global__ __launch_bounds__(256) void pre_kernel(const float* __restrict__ x,
                                                  const float* __restrict__ W,
                                                  const float* __restrict__ bvec,
                                                  float* __restrict__ xpre) {
    __shared__ float Ws[CIN * DM];   // 32 KB
    __shared__ float xs[16][CIN];    // 8 KB
    const int t = threadIdx.x;
    for (int i = t; i < CIN * DM; i += 256) Ws[i] = W[i];
    const size_t rowBase = (size_t)blockIdx.x * 16;
    for (int i = t; i < 16 * CIN; i += 256) {
        int r = i >> 7, c = i & 127;
        xs[r][c] = x[(rowBase + r) * CIN + c];
    }
    __syncthreads();
    const int col = t & 63, r0 = t >> 6;
    float acc[4];
    float bias = bvec[col];
#pragma unroll
    for (int rr = 0; rr < 4; rr++) acc[rr] = bias;
    for (int c = 0; c < CIN; c++) {
        float w = Ws[c * DM + col];
#pragma unroll
        for (int rr = 0; rr < 4; rr++) acc[rr] = fmaf(xs[r0 + 4 * rr][c], w, acc[rr]);
    }
#pragma unroll
    for (int rr = 0; rr < 4; rr++) xpre[(rowBase + r0 + 4 * rr) * DM + col] = acc[rr];
}

// ---------------- K3: fused neighbor search + KPConv + post + shortcut ----------------
__global__ __launch_bounds__(256) void conv_kernel(const float* __restrict__ pos,
                                                   const float* __restrict__ x,
                                                   const float* __restrict__ xpre,
                                                   const int* __restrict__ idxs,
                                                   const float* __restrict__ kp_pos,
                                                   const float* __restrict__ kp_W,
                                                   const float* __restrict__ W_post,
                                                   const float* __restrict__ b_post,
                                                   const float* __restrict__ W_sc,
                                                   const float* __restrict__ b_sc,
                                                   float* __restrict__ out_feat) {
    const int blk = blockIdx.x;
    const int b = blk / M_;
    const int m = blk % M_;
    const int t = threadIdx.x;

    __shared__ int   nIdx[CAP];
    __shared__ float nD2[CAP];
    __shared__ int   cntS;
    __shared__ float infl[MAXNN][K_];   // 4 KB
    __shared__ float xj[MAXNN][DM];     // 16 KB
    __shared__ float sS[K_ * DM];       // 4 KB
    __shared__ float featP[4][DM];      // 1 KB
    __shared__ float xg[CIN];           // 0.5 KB

    const float* pb = pos + (size_t)b * N_ * 3;
    const int ctr = idxs[b * M_ + m];
    const float cx = pb[ctr * 3 + 0], cy = pb[ctr * 3 + 1], cz = pb[ctr * 3 + 2];

    if (t == 0) cntS = 0;
    __syncthreads();

    // neighbor scan over all N points
    for (int j = 0; j < N_ / 256; j++) {
        int n = j * 256 + t;
        float x0 = pb[n * 3 + 0], y0 = pb[n * 3 + 1], z0 = pb[n * 3 + 2];
        float d = d2_exact(x0, y0, z0, cx, cy, cz);
        if (d <= R2) {
            int p = atomicAdd(&cntS, 1);
            if (p < CAP) { nIdx[p] = n; nD2[p] = d; }
        }
    }
    __syncthreads();
    int cnt = cntS; if (cnt > CAP) cnt = CAP;
    if (cnt > MAXNN) {
        // rare path: keep the 64 lexicographically-smallest (d2, idx) = stable top_k
        if (t == 0) {
            for (int s = 0; s < MAXNN; s++) {
                int best = s;
                for (int q = s + 1; q < cnt; q++) {
                    if (nD2[q] < nD2[best] || (nD2[q] == nD2[best] && nIdx[q] < nIdx[best])) best = q;
                }
                float td = nD2[best]; nD2[best] = nD2[s]; nD2[s] = td;
                int ti = nIdx[best]; nIdx[best] = nIdx[s]; nIdx[s] = ti;
            }
        }
        __syncthreads();
        cnt = MAXNN;
    }

    // influence weights (one thread per neighbor)
    if (t < cnt) {
        int n = nIdx[t];
        float rx = pb[n * 3 + 0] - cx, ry = pb[n * 3 + 1] - cy, rz = pb[n * 3 + 2] - cz;
#pragma unroll
        for (int k = 0; k < K_; k++) {
            float dx = rx - kp_pos[k * 3 + 0];
            float dy = ry - kp_pos[k * 3 + 1];
            float dz = rz - kp_pos[k * 3 + 2];
            float dist = sqrtf(dx * dx + dy * dy + dz * dz + 1e-12f);
            infl[t][k] = fmaxf(1.0f - dist / EXT, 0.0f);
        }
    }
    // stage gathered neighbor features
    for (int i = t; i < cnt * DM; i += 256) {
        int e = i >> 6, d = i & 63;
        xj[e][d] = xpre[((size_t)b * N_ + nIdx[e]) * DM + d];
    }
    __syncthreads();

    // s[k][d] = sum_e infl[e][k] * xj[e][d]
#pragma unroll
    for (int p = 0; p < 4; p++) {
        int pair = t + p * 256;
        int k = pair >> 6, d = pair & 63;
        float acc = 0.f;
        for (int e = 0; e < cnt; e++) acc = fmaf(infl[e][k], xj[e][d], acc);
        sS[pair] = acc;
    }
    __syncthreads();

    // feat[d'] = sum_{k,d} s[k][d] * kp_W[k][d][d']  (4-way k-split)
    {
        int dprime = t & 63, ks = t >> 6;
        float acc = 0.f;
        for (int k = ks * 4; k < ks * 4 + 4; k++) {
            const float* kw = kp_W + ((size_t)k * DM) * DM + dprime;
#pragma unroll
            for (int d = 0; d < DM; d++) acc = fmaf(sS[k * DM + d], kw[d * DM], acc);
        }
        featP[ks][dprime] = acc;
    }
    __syncthreads();
    if (t < DM) featP[0][t] = featP[0][t] + featP[1][t] + featP[2][t] + featP[3][t];
    if (t < CIN) xg[t] = x[((size_t)b * N_ + ctr) * CIN + t];
    __syncthreads();

    // out[o] = feat @ W_post + b_post + x[ctr] @ W_sc + b_sc
    {
        const int o = t;
        float acc = b_post[o] + b_sc[o];
#pragma unroll 8
        for (int d = 0; d < DM; d++) acc = fmaf(featP[0][d], W_post[d * COUT + o], acc);
#pragma unroll 8
        for (int c = 0; c < CIN; c++) acc = fmaf(xg[c], W_sc[c * COUT + o], acc);
        out_feat[((size_t)(b * M_ + m)) * COUT + o] = acc;
    }
}

extern "C" void kernel_launch(void* const* d_in, const int* in_sizes, int n_in,
                              void* d_out, int out_size, void* d_ws, size_t ws_size,
                              hipStream_t stream) {
    const float* x      = (const float*)d_in[0];
    const float* pos    = (const float*)d_in[1];
    const float* W_pre  = (const float*)d_in[2];
    const float* b_pre  = (const float*)d_in[3];
    const float* kp_pos = (const float*)d_in[4];
    const float* kp_W   = (const float*)d_in[5];
    const float* W_post = (const float*)d_in[6];
    const float* b_post = (const float*)d_in[7];
    const float* W_sc   = (const float*)d_in[8];
    const float* b_sc   = (const float*)d_in[9];

    float* out_feat = (float*)d_out;
    float* out_pos  = (float*)d_out + (size_t)B_ * M_ * COUT;

    int*   idxs = (int*)d_ws;
    float* xpre = (float*)((char*)d_ws + 64 * 1024);

    fps_kernel<<<B_, 1024, 0, stream>>>(pos, idxs, out_pos);
    pre_kernel<<<(B_ * N_) / 16, 256, 0, stream>>>(x, W_pre, b_pre, xpre);
    conv_kernel<<<B_ * M_, 256, 0, stream>>>(pos, x, xpre, idxs, kp_pos, kp_W,
                                             W_post, b_post, W_sc, b_sc, out_feat);
}

// Round 2
// 3519.838 us; speedup vs baseline: 1.7321x; 1.7321x over previous
//
#include <hip/hip_runtime.h>

#define B_    4
#define N_    8192
#define CIN   128
#define COUT  256
#define M_    2048
#define K_    16
#define DM    64
#define MAXNN 64
#define CAP   128
#define R2    0.01f
#define EXT   0.1f

// Exact-rounded squared distance matching numpy's op order: (dx*dx + dy*dy) + dz*dz
__device__ __forceinline__ float d2_exact(float ax, float ay, float az,
                                          float bx, float by, float bz) {
    float dx = ax - bx, dy = ay - by, dz = az - bz;
    return __fadd_rn(__fadd_rn(__fmul_rn(dx, dx), __fmul_rn(dy, dy)), __fmul_rn(dz, dz));
}

// ---------------- K1: farthest point sampling (one block per cloud) ----------------
// 256 threads (4 waves, one per SIMD). 32 register-resident points per lane.
// Argmax carried as packed u64 key: (float_bits(mind) << 32) | (0xFFFFFFFF - idx)
//   -> u64 max == numpy argmax (max value, first/smallest index on bit-equal ties).
// One barrier per iteration; cross-wave reduce done redundantly by every thread
// (4 LDS entries); double-buffered slots by (m&1) make the single barrier safe.
__global__ __launch_bounds__(256, 1) void fps_kernel(const float* __restrict__ pos,
                                                     int* __restrict__ idx_out,
                                                     float* __restrict__ out_pos) {
    const int b = blockIdx.x;
    const int t = threadIdx.x;
    const float* pb = pos + (size_t)b * N_ * 3;

    __shared__ unsigned long long keyS[2][4];
    __shared__ float4 posS[2][4];

    float px[32], py[32], pz[32], mind[32];
#pragma unroll
    for (int j = 0; j < 32; j++) {
        int n = t + j * 256;
        px[j] = pb[n * 3 + 0];
        py[j] = pb[n * 3 + 1];
        pz[j] = pb[n * 3 + 2];
        mind[j] = 1e30f;
    }
    float cx = pb[0], cy = pb[1], cz = pb[2];
    if (t == 0) {
        idx_out[b * M_ + 0] = 0;
        float* op = out_pos + ((size_t)(b * M_ + 0)) * 3;
        op[0] = cx; op[1] = cy; op[2] = cz;
    }

    for (int m = 1; m < M_; m++) {
        // fused mind-update + lane-local argmax (ascending j => ascending global idx,
        // strict > keeps the first max => smallest index on ties)
        float bv = -1.0f; int bn = 0; float bx = 0.f, by = 0.f, bz = 0.f;
#pragma unroll
        for (int j = 0; j < 32; j++) {
            float d = d2_exact(px[j], py[j], pz[j], cx, cy, cz);
            d = fminf(mind[j], d);
            mind[j] = d;
            if (d > bv) { bv = d; bn = t + j * 256; bx = px[j]; by = py[j]; bz = pz[j]; }
        }
        unsigned long long key = ((unsigned long long)__float_as_uint(bv) << 32)
                               | (unsigned long long)(0xFFFFFFFFu - (unsigned)bn);
        // wave64 butterfly on the packed key, carrying winner position alongside
#pragma unroll
        for (int off = 1; off < 64; off <<= 1) {
            unsigned long long ok = __shfl_xor(key, off);
            float ox = __shfl_xor(bx, off);
            float oy = __shfl_xor(by, off);
            float oz = __shfl_xor(bz, off);
            if (ok > key) { key = ok; bx = ox; by = oy; bz = oz; }
        }
        const int buf = m & 1;
        const int w = t >> 6;
        if ((t & 63) == 0) {
            keyS[buf][w] = key;
            posS[buf][w] = make_float4(bx, by, bz, 0.f);
        }
        __syncthreads();
        unsigned long long k0 = keyS[buf][0], k1 = keyS[buf][1],
                           k2 = keyS[buf][2], k3 = keyS[buf][3];
        float4 p0 = posS[buf][0], p1 = posS[buf][1],
               p2 = posS[buf][2], p3 = posS[buf][3];
        if (k1 > k0) { k0 = k1; p0 = p1; }
        if (k3 > k2) { k2 = k3; p2 = p3; }
        if (k2 > k0) { k0 = k2; p0 = p2; }
        cx = p0.x; cy = p0.y; cz = p0.z;
        if (t == 0) {
            idx_out[b * M_ + m] = (int)(0xFFFFFFFFu - (unsigned)(k0 & 0xFFFFFFFFull));
            float* op = out_pos + ((size_t)(b * M_ + m)) * 3;
            op[0] = cx; op[1] = cy; op[2] = cz;
        }
    }
}

// ---------------- K2: pre-MLP  x_pre = x @ W_pre + b_pre ----------------
__global__ __launch_bounds__(256) void pre_kernel(const float* __restrict__ x,
                                                  const float* __restrict__ W,
                                                  const float* __restrict__ bvec,
                                                  float* __restrict__ xpre) {
    __shared__ float Ws[CIN * DM];   // 32 KB
    __shared__ float xs[16][CIN];    // 8 KB
    const int t = threadIdx.x;
    for (int i = t; i < CIN * DM; i += 256) Ws[i] = W[i];
    const size_t rowBase = (size_t)blockIdx.x * 16;
    for (int i = t; i < 16 * CIN; i += 256) {
        int r = i >> 7, c = i & 127;
        xs[r][c] = x[(rowBase + r) * CIN + c];
    }
    __syncthreads();
    const int col = t & 63, r0 = t >> 6;
    float acc[4];
    float bias = bvec[col];
#pragma unroll
    for (int rr = 0; rr < 4; rr++) acc[rr] = bias;
    for (int c = 0; c < CIN; c++) {
        float w = Ws[c * DM + col];
#pragma unroll
        for (int rr = 0; rr < 4; rr++) acc[rr] = fmaf(xs[r0 + 4 * rr][c], w, acc[rr]);
    }
#pragma unroll
    for (int rr = 0; rr < 4; rr++) xpre[(rowBase + r0 + 4 * rr) * DM + col] = acc[rr];
}

// ---------------- K3: fused neighbor search + KPConv + post + shortcut ----------------
__global__ __launch_bounds__(256) void conv_kernel(const float* __restrict__ pos,
                                                   const float* __restrict__ x,
                                                   const float* __restrict__ xpre,
                                                   const int* __restrict__ idxs,
                                                   const float* __restrict__ kp_pos,
                                                   const float* __restrict__ kp_W,
                                                   const float* __restrict__ W_post,
                                                   const float* __restrict__ b_post,
                                                   const float* __restrict__ W_sc,
                                                   const float* __restrict__ b_sc,
                                                   float* __restrict__ out_feat) {
    const int blk = blockIdx.x;
    const int b = blk / M_;
    const int m = blk % M_;
    const int t = threadIdx.x;

    __shared__ int   nIdx[CAP];
    __shared__ float nD2[CAP];
    __shared__ int   cntS;
    __shared__ float infl[MAXNN][K_];   // 4 KB
    __shared__ float xj[MAXNN][DM];     // 16 KB
    __shared__ float sS[K_ * DM];       // 4 KB
    __shared__ float featP[4][DM];      // 1 KB
    __shared__ float xg[CIN];           // 0.5 KB

    const float* pb = pos + (size_t)b * N_ * 3;
    const int ctr = idxs[b * M_ + m];
    const float cx = pb[ctr * 3 + 0], cy = pb[ctr * 3 + 1], cz = pb[ctr * 3 + 2];

    if (t == 0) cntS = 0;
    __syncthreads();

    // neighbor scan over all N points
    for (int j = 0; j < N_ / 256; j++) {
        int n = j * 256 + t;
        float x0 = pb[n * 3 + 0], y0 = pb[n * 3 + 1], z0 = pb[n * 3 + 2];
        float d = d2_exact(x0, y0, z0, cx, cy, cz);
        if (d <= R2) {
            int p = atomicAdd(&cntS, 1);
            if (p < CAP) { nIdx[p] = n; nD2[p] = d; }
        }
    }
    __syncthreads();
    int cnt = cntS; if (cnt > CAP) cnt = CAP;
    if (cnt > MAXNN) {
        // rare path: keep the 64 lexicographically-smallest (d2, idx) = stable top_k
        if (t == 0) {
            for (int s = 0; s < MAXNN; s++) {
                int best = s;
                for (int q = s + 1; q < cnt; q++) {
                    if (nD2[q] < nD2[best] || (nD2[q] == nD2[best] && nIdx[q] < nIdx[best])) best = q;
                }
                float td = nD2[best]; nD2[best] = nD2[s]; nD2[s] = td;
                int ti = nIdx[best]; nIdx[best] = nIdx[s]; nIdx[s] = ti;
            }
        }
        __syncthreads();
        cnt = MAXNN;
    }

    // influence weights (one thread per neighbor)
    if (t < cnt) {
        int n = nIdx[t];
        float rx = pb[n * 3 + 0] - cx, ry = pb[n * 3 + 1] - cy, rz = pb[n * 3 + 2] - cz;
#pragma unroll
        for (int k = 0; k < K_; k++) {
            float dx = rx - kp_pos[k * 3 + 0];
            float dy = ry - kp_pos[k * 3 + 1];
            float dz = rz - kp_pos[k * 3 + 2];
            float dist = sqrtf(dx * dx + dy * dy + dz * dz + 1e-12f);
            infl[t][k] = fmaxf(1.0f - dist / EXT, 0.0f);
        }
    }
    // stage gathered neighbor features
    for (int i = t; i < cnt * DM; i += 256) {
        int e = i >> 6, d = i & 63;
        xj[e][d] = xpre[((size_t)b * N_ + nIdx[e]) * DM + d];
    }
    __syncthreads();

    // s[k][d] = sum_e infl[e][k] * xj[e][d]
#pragma unroll
    for (int p = 0; p < 4; p++) {
        int pair = t + p * 256;
        int k = pair >> 6, d = pair & 63;
        float acc = 0.f;
        for (int e = 0; e < cnt; e++) acc = fmaf(infl[e][k], xj[e][d], acc);
        sS[pair] = acc;
    }
    __syncthreads();

    // feat[d'] = sum_{k,d} s[k][d] * kp_W[k][d][d']  (4-way k-split)
    {
        int dprime = t & 63, ks = t >> 6;
        float acc = 0.f;
        for (int k = ks * 4; k < ks * 4 + 4; k++) {
            const float* kw = kp_W + ((size_t)k * DM) * DM + dprime;
#pragma unroll
            for (int d = 0; d < DM; d++) acc = fmaf(sS[k * DM + d], kw[d * DM], acc);
        }
        featP[ks][dprime] = acc;
    }
    __syncthreads();
    if (t < DM) featP[0][t] = featP[0][t] + featP[1][t] + featP[2][t] + featP[3][t];
    if (t < CIN) xg[t] = x[((size_t)b * N_ + ctr) * CIN + t];
    __syncthreads();

    // out[o] = feat @ W_post + b_post + x[ctr] @ W_sc + b_sc
    {
        const int o = t;
        float acc = b_post[o] + b_sc[o];
#pragma unroll 8
        for (int d = 0; d < DM; d++) acc = fmaf(featP[0][d], W_post[d * COUT + o], acc);
#pragma unroll 8
        for (int c = 0; c < CIN; c++) acc = fmaf(xg[c], W_sc[c * COUT + o], acc);
        out_feat[((size_t)(b * M_ + m)) * COUT + o] = acc;
    }
}

extern "C" void kernel_launch(void* const* d_in, const int* in_sizes, int n_in,
                              void* d_out, int out_size, void* d_ws, size_t ws_size,
                              hipStream_t stream) {
    const float* x      = (const float*)d_in[0];
    const float* pos    = (const float*)d_in[1];
    const float* W_pre  = (const float*)d_in[2];
    const float* b_pre  = (const float*)d_in[3];
    const float* kp_pos = (const float*)d_in[4];
    const float* kp_W   = (const float*)d_in[5];
    const float* W_post = (const float*)d_in[6];
    const float* b_post = (const float*)d_in[7];
    const float* W_sc   = (const float*)d_in[8];
    const float* b_sc   = (const float*)d_in[9];

    float* out_feat = (float*)d_out;
    float* out_pos  = (float*)d_out + (size_t)B_ * M_ * COUT;

    int*   idxs = (int*)d_ws;
    float* xpre = (float*)((char*)d_ws + 64 * 1024);

    fps_kernel<<<B_, 256, 0, stream>>>(pos, idxs, out_pos);
    pre_kernel<<<(B_ * N_) / 16, 256, 0, stream>>>(x, W_pre, b_pre, xpre);
    conv_kernel<<<B_ * M_, 256, 0, stream>>>(pos, x, xpre, idxs, kp_pos, kp_W,
                                             W_post, b_post, W_sc, b_sc, out_feat);
}

// Round 3
// 3480.429 us; speedup vs baseline: 1.7517x; 1.0113x over previous
//
#include <hip/hip_runtime.h>

#define B_    4
#define N_    8192
#define CIN   128
#define COUT  256
#define M_    2048
#define K_    16
#define DM    64
#define MAXNN 64
#define CAP   128
#define R2    0.01f
#define EXT   0.1f

// Exact-rounded squared distance matching numpy's op order: (dx*dx + dy*dy) + dz*dz
__device__ __forceinline__ float d2_exact(float ax, float ay, float az,
                                          float bx, float by, float bz) {
    float dx = ax - bx, dy = ay - by, dz = az - bz;
    return __fadd_rn(__fadd_rn(__fmul_rn(dx, dx), __fmul_rn(dy, dy)), __fmul_rn(dz, dz));
}

// ---------------- K1: farthest point sampling (one block per cloud) ----------------
// 256 threads (4 waves). 32 register-resident points per lane (as float2 pairs).
// Argmax key: (float_bits(mind) << 32) | (0xFFFFFFFF - idx)  -> u64 max == numpy argmax.
// In-wave reduction via DPP (row_shr + row_bcast, VALU-latency) instead of ds_bpermute.
// Result collects in lane 63 -> readlane -> one LDS slot per wave; single barrier per
// iteration with (m&1) double-buffered slots.
#define DPP_XSTEP(CTRL)                                                                   \
    {                                                                                     \
        unsigned tlo = (unsigned)__builtin_amdgcn_update_dpp(0, (int)klo, CTRL, 0xF, 0xF, true); \
        unsigned thi = (unsigned)__builtin_amdgcn_update_dpp(0, (int)khi, CTRL, 0xF, 0xF, true); \
        unsigned txu = (unsigned)__builtin_amdgcn_update_dpp(0, (int)xu, CTRL, 0xF, 0xF, true);  \
        unsigned tyu = (unsigned)__builtin_amdgcn_update_dpp(0, (int)yu, CTRL, 0xF, 0xF, true);  \
        unsigned tzu = (unsigned)__builtin_amdgcn_update_dpp(0, (int)zu, CTRL, 0xF, 0xF, true);  \
        unsigned long long tk = ((unsigned long long)thi << 32) | tlo;                    \
        unsigned long long ck = ((unsigned long long)khi << 32) | klo;                    \
        if (tk > ck) { klo = tlo; khi = thi; xu = txu; yu = tyu; zu = tzu; }              \
    }

__global__ __launch_bounds__(256, 1) void fps_kernel(const float* __restrict__ pos,
                                                     int* __restrict__ idx_out,
                                                     float* __restrict__ out_pos) {
    const int b = blockIdx.x;
    const int t = threadIdx.x;
    const float* pb = pos + (size_t)b * N_ * 3;

    __shared__ unsigned long long keyS[2][4];
    __shared__ float4 posS[2][4];

    float2 px2[16], py2[16], pz2[16], mind2[16];
#pragma unroll
    for (int jj = 0; jj < 16; jj++) {
        int n0 = t + (2 * jj) * 256, n1 = n0 + 256;
        px2[jj] = make_float2(pb[n0 * 3 + 0], pb[n1 * 3 + 0]);
        py2[jj] = make_float2(pb[n0 * 3 + 1], pb[n1 * 3 + 1]);
        pz2[jj] = make_float2(pb[n0 * 3 + 2], pb[n1 * 3 + 2]);
        mind2[jj] = make_float2(1e30f, 1e30f);
    }
    float cx = pb[0], cy = pb[1], cz = pb[2];
    if (t == 0) {
        idx_out[b * M_ + 0] = 0;
        float* op = out_pos + ((size_t)(b * M_ + 0)) * 3;
        op[0] = cx; op[1] = cy; op[2] = cz;
    }

    for (int m = 1; m < M_; m++) {
        // fused mind-update + lane-local argmax; plain float ops with contraction OFF
        // (exact numpy rounding) so the compiler can use packed f32.
        float bv = -1.0f; int bn = 0; float bx = 0.f, by = 0.f, bz = 0.f;
#pragma unroll
        for (int jj = 0; jj < 16; jj++) {
#pragma clang fp contract(off)
            float dx0 = px2[jj].x - cx, dy0 = py2[jj].x - cy, dz0 = pz2[jj].x - cz;
            float dx1 = px2[jj].y - cx, dy1 = py2[jj].y - cy, dz1 = pz2[jj].y - cz;
            float d0 = (dx0 * dx0 + dy0 * dy0) + dz0 * dz0;
            float d1 = (dx1 * dx1 + dy1 * dy1) + dz1 * dz1;
            d0 = fminf(mind2[jj].x, d0);
            d1 = fminf(mind2[jj].y, d1);
            mind2[jj].x = d0; mind2[jj].y = d1;
            if (d0 > bv) { bv = d0; bn = t + (2 * jj) * 256;     bx = px2[jj].x; by = py2[jj].x; bz = pz2[jj].x; }
            if (d1 > bv) { bv = d1; bn = t + (2 * jj + 1) * 256; bx = px2[jj].y; by = py2[jj].y; bz = pz2[jj].y; }
        }
        unsigned klo = 0xFFFFFFFFu - (unsigned)bn;
        unsigned khi = __float_as_uint(bv);
        unsigned xu = __float_as_uint(bx), yu = __float_as_uint(by), zu = __float_as_uint(bz);

        // wave64 max-reduce via DPP; winner lands in lane 63
        DPP_XSTEP(0x111)  // row_shr:1
        DPP_XSTEP(0x112)  // row_shr:2
        DPP_XSTEP(0x114)  // row_shr:4
        DPP_XSTEP(0x118)  // row_shr:8
        DPP_XSTEP(0x142)  // row_bcast:15
        DPP_XSTEP(0x143)  // row_bcast:31

        unsigned wlo = (unsigned)__builtin_amdgcn_readlane((int)klo, 63);
        unsigned whi = (unsigned)__builtin_amdgcn_readlane((int)khi, 63);
        unsigned wxu = (unsigned)__builtin_amdgcn_readlane((int)xu, 63);
        unsigned wyu = (unsigned)__builtin_amdgcn_readlane((int)yu, 63);
        unsigned wzu = (unsigned)__builtin_amdgcn_readlane((int)zu, 63);

        const int buf = m & 1;
        const int w = t >> 6;
        if ((t & 63) == 0) {
            keyS[buf][w] = ((unsigned long long)whi << 32) | wlo;
            posS[buf][w] = make_float4(__uint_as_float(wxu), __uint_as_float(wyu),
                                       __uint_as_float(wzu), 0.f);
        }
        __syncthreads();
        unsigned long long k0 = keyS[buf][0], k1 = keyS[buf][1],
                           k2 = keyS[buf][2], k3 = keyS[buf][3];
        float4 p0 = posS[buf][0], p1 = posS[buf][1],
               p2 = posS[buf][2], p3 = posS[buf][3];
        if (k1 > k0) { k0 = k1; p0 = p1; }
        if (k3 > k2) { k2 = k3; p2 = p3; }
        if (k2 > k0) { k0 = k2; p0 = p2; }
        cx = p0.x; cy = p0.y; cz = p0.z;
        if (t == 0) {
            idx_out[b * M_ + m] = (int)(0xFFFFFFFFu - (unsigned)(k0 & 0xFFFFFFFFull));
            float* op = out_pos + ((size_t)(b * M_ + m)) * 3;
            op[0] = cx; op[1] = cy; op[2] = cz;
        }
    }
}

// ---------------- K2: pre-MLP  x_pre = x @ W_pre + b_pre ----------------
__global__ __launch_bounds__(256) void pre_kernel(const float* __restrict__ x,
                                                  const float* __restrict__ W,
                                                  const float* __restrict__ bvec,
                                                  float* __restrict__ xpre) {
    __shared__ float Ws[CIN * DM];   // 32 KB
    __shared__ float xs[16][CIN];    // 8 KB
    const int t = threadIdx.x;
    for (int i = t; i < CIN * DM; i += 256) Ws[i] = W[i];
    const size_t rowBase = (size_t)blockIdx.x * 16;
    for (int i = t; i < 16 * CIN; i += 256) {
        int r = i >> 7, c = i & 127;
        xs[r][c] = x[(rowBase + r) * CIN + c];
    }
    __syncthreads();
    const int col = t & 63, r0 = t >> 6;
    float acc[4];
    float bias = bvec[col];
#pragma unroll
    for (int rr = 0; rr < 4; rr++) acc[rr] = bias;
    for (int c = 0; c < CIN; c++) {
        float w = Ws[c * DM + col];
#pragma unroll
        for (int rr = 0; rr < 4; rr++) acc[rr] = fmaf(xs[r0 + 4 * rr][c], w, acc[rr]);
    }
#pragma unroll
    for (int rr = 0; rr < 4; rr++) xpre[(rowBase + r0 + 4 * rr) * DM + col] = acc[rr];
}

// ---------------- K3: fused neighbor search + KPConv + post + shortcut ----------------
__global__ __launch_bounds__(256) void conv_kernel(const float* __restrict__ pos,
                                                   const float* __restrict__ x,
                                                   const float* __restrict__ xpre,
                                                   const int* __restrict__ idxs,
                                                   const float* __restrict__ kp_pos,
                                                   const float* __restrict__ kp_W,
                                                   const float* __restrict__ W_post,
                                                   const float* __restrict__ b_post,
                                                   const float* __restrict__ W_sc,
                                                   const float* __restrict__ b_sc,
                                                   float* __restrict__ out_feat) {
    const int blk = blockIdx.x;
    const int b = blk / M_;
    const int m = blk % M_;
    const int t = threadIdx.x;

    __shared__ int   nIdx[CAP];
    __shared__ float nD2[CAP];
    __shared__ int   cntS;
    __shared__ float infl[MAXNN][K_];   // 4 KB
    __shared__ float xj[MAXNN][DM];     // 16 KB
    __shared__ float sS[K_ * DM];       // 4 KB
    __shared__ float featP[4][DM];      // 1 KB
    __shared__ float xg[CIN];           // 0.5 KB

    const float* pb = pos + (size_t)b * N_ * 3;
    const int ctr = idxs[b * M_ + m];
    const float cx = pb[ctr * 3 + 0], cy = pb[ctr * 3 + 1], cz = pb[ctr * 3 + 2];

    if (t == 0) cntS = 0;
    __syncthreads();

    // neighbor scan over all N points
    for (int j = 0; j < N_ / 256; j++) {
        int n = j * 256 + t;
        float x0 = pb[n * 3 + 0], y0 = pb[n * 3 + 1], z0 = pb[n * 3 + 2];
        float d = d2_exact(x0, y0, z0, cx, cy, cz);
        if (d <= R2) {
            int p = atomicAdd(&cntS, 1);
            if (p < CAP) { nIdx[p] = n; nD2[p] = d; }
        }
    }
    __syncthreads();
    int cnt = cntS; if (cnt > CAP) cnt = CAP;
    if (cnt > MAXNN) {
        // rare path: keep the 64 lexicographically-smallest (d2, idx) = stable top_k
        if (t == 0) {
            for (int s = 0; s < MAXNN; s++) {
                int best = s;
                for (int q = s + 1; q < cnt; q++) {
                    if (nD2[q] < nD2[best] || (nD2[q] == nD2[best] && nIdx[q] < nIdx[best])) best = q;
                }
                float td = nD2[best]; nD2[best] = nD2[s]; nD2[s] = td;
                int ti = nIdx[best]; nIdx[best] = nIdx[s]; nIdx[s] = ti;
            }
        }
        __syncthreads();
        cnt = MAXNN;
    }

    // influence weights (one thread per neighbor)
    if (t < cnt) {
        int n = nIdx[t];
        float rx = pb[n * 3 + 0] - cx, ry = pb[n * 3 + 1] - cy, rz = pb[n * 3 + 2] - cz;
#pragma unroll
        for (int k = 0; k < K_; k++) {
            float dx = rx - kp_pos[k * 3 + 0];
            float dy = ry - kp_pos[k * 3 + 1];
            float dz = rz - kp_pos[k * 3 + 2];
            float dist = sqrtf(dx * dx + dy * dy + dz * dz + 1e-12f);
            infl[t][k] = fmaxf(1.0f - dist / EXT, 0.0f);
        }
    }
    // stage gathered neighbor features
    for (int i = t; i < cnt * DM; i += 256) {
        int e = i >> 6, d = i & 63;
        xj[e][d] = xpre[((size_t)b * N_ + nIdx[e]) * DM + d];
    }
    __syncthreads();

    // s[k][d] = sum_e infl[e][k] * xj[e][d]
#pragma unroll
    for (int p = 0; p < 4; p++) {
        int pair = t + p * 256;
        int k = pair >> 6, d = pair & 63;
        float acc = 0.f;
        for (int e = 0; e < cnt; e++) acc = fmaf(infl[e][k], xj[e][d], acc);
        sS[pair] = acc;
    }
    __syncthreads();

    // feat[d'] = sum_{k,d} s[k][d] * kp_W[k][d][d']  (4-way k-split)
    {
        int dprime = t & 63, ks = t >> 6;
        float acc = 0.f;
        for (int k = ks * 4; k < ks * 4 + 4; k++) {
            const float* kw = kp_W + ((size_t)k * DM) * DM + dprime;
#pragma unroll
            for (int d = 0; d < DM; d++) acc = fmaf(sS[k * DM + d], kw[d * DM], acc);
        }
        featP[ks][dprime] = acc;
    }
    __syncthreads();
    if (t < DM) featP[0][t] = featP[0][t] + featP[1][t] + featP[2][t] + featP[3][t];
    if (t < CIN) xg[t] = x[((size_t)b * N_ + ctr) * CIN + t];
    __syncthreads();

    // out[o] = feat @ W_post + b_post + x[ctr] @ W_sc + b_sc
    {
        const int o = t;
        float acc = b_post[o] + b_sc[o];
#pragma unroll 8
        for (int d = 0; d < DM; d++) acc = fmaf(featP[0][d], W_post[d * COUT + o], acc);
#pragma unroll 8
        for (int c = 0; c < CIN; c++) acc = fmaf(xg[c], W_sc[c * COUT + o], acc);
        out_feat[((size_t)(b * M_ + m)) * COUT + o] = acc;
    }
}

extern "C" void kernel_launch(void* const* d_in, const int* in_sizes, int n_in,
                              void* d_out, int out_size, void* d_ws, size_t ws_size,
                              hipStream_t stream) {
    const float* x      = (const float*)d_in[0];
    const float* pos    = (const float*)d_in[1];
    const float* W_pre  = (const float*)d_in[2];
    const float* b_pre  = (const float*)d_in[3];
    const float* kp_pos = (const float*)d_in[4];
    const float* kp_W   = (const float*)d_in[5];
    const float* W_post = (const float*)d_in[6];
    const float* b_post = (const float*)d_in[7];
    const float* W_sc   = (const float*)d_in[8];
    const float* b_sc   = (const float*)d_in[9];

    float* out_feat = (float*)d_out;
    float* out_pos  = (float*)d_out + (size_t)B_ * M_ * COUT;

    int*   idxs = (int*)d_ws;
    float* xpre = (float*)((char*)d_ws + 64 * 1024);

    fps_kernel<<<B_, 256, 0, stream>>>(pos, idxs, out_pos);
    pre_kernel<<<(B_ * N_) / 16, 256, 0, stream>>>(x, W_pre, b_pre, xpre);
    conv_kernel<<<B_ * M_, 256, 0, stream>>>(pos, x, xpre, idxs, kp_pos, kp_W,
                                             W_post, b_post, W_sc, b_sc, out_feat);
}

// Round 4
// 2389.238 us; speedup vs baseline: 2.5517x; 1.4567x over previous
//
#include <hip/hip_runtime.h>

#define B_    4
#define N_    8192
#define CIN   128
#define COUT  256
#define M_    2048
#define K_    16
#define DM    64
#define MAXNN 64
#define CAP   128
#define R2    0.01f
#define EXT   0.1f

// Exact-rounded squared distance matching numpy's op order: (dx*dx + dy*dy) + dz*dz
__device__ __forceinline__ float d2_exact(float ax, float ay, float az,
                                          float bx, float by, float bz) {
    float dx = ax - bx, dy = ay - by, dz = az - bz;
    return __fadd_rn(__fadd_rn(__fmul_rn(dx, dx), __fmul_rn(dy, dy)), __fmul_rn(dz, dz));
}

// ---------------- K1: farthest point sampling (one block per cloud) ----------------
// 512 threads (8 waves), 16 register-resident points per lane => 64 data VGPRs, no spill.
// Reduction carries ONLY the packed u64 key (float_bits(mind) << 32) | (~idx):
// u64 max == numpy argmax (max value, smallest index on bit-equal ties).
// Wave reduce: 6 DPP steps (row_shr/row_bcast), winner lands in lane 63 which writes
// its wave's slot; single (m&1)-double-buffered barrier; every thread reduces the
// 8 slots and loads the winning center from global (same-address broadcast, L1/L2).
#define DPP_STEP2(CTRL)                                                                   \
    {                                                                                     \
        unsigned tlo = (unsigned)__builtin_amdgcn_update_dpp(0, (int)klo, CTRL, 0xF, 0xF, true); \
        unsigned thi = (unsigned)__builtin_amdgcn_update_dpp(0, (int)khi, CTRL, 0xF, 0xF, true); \
        unsigned long long tk = ((unsigned long long)thi << 32) | tlo;                    \
        unsigned long long ck = ((unsigned long long)khi << 32) | klo;                    \
        if (tk > ck) { klo = tlo; khi = thi; }                                            \
    }

__global__ __launch_bounds__(512) void fps_kernel(const float* __restrict__ pos,
                                                  int* __restrict__ idx_out,
                                                  float* __restrict__ out_pos) {
    const int b = blockIdx.x;
    const int t = threadIdx.x;
    const float* pb = pos + (size_t)b * N_ * 3;

    __shared__ unsigned long long keyS[2][8];

    float px[16], py[16], pz[16], mind[16];
#pragma unroll
    for (int j = 0; j < 16; j++) {
        int n = t + j * 512;
        px[j] = pb[n * 3 + 0];
        py[j] = pb[n * 3 + 1];
        pz[j] = pb[n * 3 + 2];
        mind[j] = 1e30f;
    }
    float cx = pb[0], cy = pb[1], cz = pb[2];
    if (t == 0) {
        idx_out[b * M_ + 0] = 0;
        float* op = out_pos + ((size_t)(b * M_ + 0)) * 3;
        op[0] = cx; op[1] = cy; op[2] = cz;
    }

    for (int m = 1; m < M_; m++) {
        // fused mind-update + lane-local argmax (ascending j => ascending global idx,
        // strict > keeps the first max => smallest index on ties)
        float bv = -1.0f; int bn = 0;
#pragma unroll
        for (int j = 0; j < 16; j++) {
#pragma clang fp contract(off)
            float dx = px[j] - cx, dy = py[j] - cy, dz = pz[j] - cz;
            float d = (dx * dx + dy * dy) + dz * dz;
            d = fminf(mind[j], d);
            mind[j] = d;
            if (d > bv) { bv = d; bn = t + j * 512; }
        }
        unsigned klo = 0xFFFFFFFFu - (unsigned)bn;
        unsigned khi = __float_as_uint(bv);

        // wave64 max-reduce via DPP; winner lands in lane 63
        DPP_STEP2(0x111)  // row_shr:1
        DPP_STEP2(0x112)  // row_shr:2
        DPP_STEP2(0x114)  // row_shr:4
        DPP_STEP2(0x118)  // row_shr:8
        DPP_STEP2(0x142)  // row_bcast:15
        DPP_STEP2(0x143)  // row_bcast:31

        const int buf = m & 1;
        if ((t & 63) == 63) {
            keyS[buf][t >> 6] = ((unsigned long long)khi << 32) | klo;
        }
        __syncthreads();
        unsigned long long k0 = keyS[buf][0];
#pragma unroll
        for (int w = 1; w < 8; w++) {
            unsigned long long kw = keyS[buf][w];
            if (kw > k0) k0 = kw;
        }
        const unsigned widx = 0xFFFFFFFFu - (unsigned)(k0 & 0xFFFFFFFFull);
        const float* cp = pb + (size_t)widx * 3;
        cx = cp[0]; cy = cp[1]; cz = cp[2];
        if (t == 0) {
            idx_out[b * M_ + m] = (int)widx;
            float* op = out_pos + ((size_t)(b * M_ + m)) * 3;
            op[0] = cx; op[1] = cy; op[2] = cz;
        }
    }
}

// ---------------- K2: pre-MLP  x_pre = x @ W_pre + b_pre ----------------
__global__ __launch_bounds__(256) void pre_kernel(const float* __restrict__ x,
                                                  const float* __restrict__ W,
                                                  const float* __restrict__ bvec,
                                                  float* __restrict__ xpre) {
    __shared__ float Ws[CIN * DM];   // 32 KB
    __shared__ float xs[16][CIN];    // 8 KB
    const int t = threadIdx.x;
    for (int i = t; i < CIN * DM; i += 256) Ws[i] = W[i];
    const size_t rowBase = (size_t)blockIdx.x * 16;
    for (int i = t; i < 16 * CIN; i += 256) {
        int r = i >> 7, c = i & 127;
        xs[r][c] = x[(rowBase + r) * CIN + c];
    }
    __syncthreads();
    const int col = t & 63, r0 = t >> 6;
    float acc[4];
    float bias = bvec[col];
#pragma unroll
    for (int rr = 0; rr < 4; rr++) acc[rr] = bias;
    for (int c = 0; c < CIN; c++) {
        float w = Ws[c * DM + col];
#pragma unroll
        for (int rr = 0; rr < 4; rr++) acc[rr] = fmaf(xs[r0 + 4 * rr][c], w, acc[rr]);
    }
#pragma unroll
    for (int rr = 0; rr < 4; rr++) xpre[(rowBase + r0 + 4 * rr) * DM + col] = acc[rr];
}

// ---------------- K3: fused neighbor search + KPConv + post + shortcut ----------------
__global__ __launch_bounds__(256) void conv_kernel(const float* __restrict__ pos,
                                                   const float* __restrict__ x,
                                                   const float* __restrict__ xpre,
                                                   const int* __restrict__ idxs,
                                                   const float* __restrict__ kp_pos,
                                                   const float* __restrict__ kp_W,
                                                   const float* __restrict__ W_post,
                                                   const float* __restrict__ b_post,
                                                   const float* __restrict__ W_sc,
                                                   const float* __restrict__ b_sc,
                                                   float* __restrict__ out_feat) {
    const int blk = blockIdx.x;
    const int b = blk / M_;
    const int m = blk % M_;
    const int t = threadIdx.x;

    __shared__ int   nIdx[CAP];
    __shared__ float nD2[CAP];
    __shared__ int   cntS;
    __shared__ float infl[MAXNN][K_];   // 4 KB
    __shared__ float xj[MAXNN][DM];     // 16 KB
    __shared__ float sS[K_ * DM];       // 4 KB
    __shared__ float featP[4][DM];      // 1 KB
    __shared__ float xg[CIN];           // 0.5 KB

    const float* pb = pos + (size_t)b * N_ * 3;
    const int ctr = idxs[b * M_ + m];
    const float cx = pb[ctr * 3 + 0], cy = pb[ctr * 3 + 1], cz = pb[ctr * 3 + 2];

    if (t == 0) cntS = 0;
    __syncthreads();

    // neighbor scan over all N points
    for (int j = 0; j < N_ / 256; j++) {
        int n = j * 256 + t;
        float x0 = pb[n * 3 + 0], y0 = pb[n * 3 + 1], z0 = pb[n * 3 + 2];
        float d = d2_exact(x0, y0, z0, cx, cy, cz);
        if (d <= R2) {
            int p = atomicAdd(&cntS, 1);
            if (p < CAP) { nIdx[p] = n; nD2[p] = d; }
        }
    }
    __syncthreads();
    int cnt = cntS; if (cnt > CAP) cnt = CAP;
    if (cnt > MAXNN) {
        // rare path: keep the 64 lexicographically-smallest (d2, idx) = stable top_k
        if (t == 0) {
            for (int s = 0; s < MAXNN; s++) {
                int best = s;
                for (int q = s + 1; q < cnt; q++) {
                    if (nD2[q] < nD2[best] || (nD2[q] == nD2[best] && nIdx[q] < nIdx[best])) best = q;
                }
                float td = nD2[best]; nD2[best] = nD2[s]; nD2[s] = td;
                int ti = nIdx[best]; nIdx[best] = nIdx[s]; nIdx[s] = ti;
            }
        }
        __syncthreads();
        cnt = MAXNN;
    }

    // influence weights (one thread per neighbor)
    if (t < cnt) {
        int n = nIdx[t];
        float rx = pb[n * 3 + 0] - cx, ry = pb[n * 3 + 1] - cy, rz = pb[n * 3 + 2] - cz;
#pragma unroll
        for (int k = 0; k < K_; k++) {
            float dx = rx - kp_pos[k * 3 + 0];
            float dy = ry - kp_pos[k * 3 + 1];
            float dz = rz - kp_pos[k * 3 + 2];
            float dist = sqrtf(dx * dx + dy * dy + dz * dz + 1e-12f);
            infl[t][k] = fmaxf(1.0f - dist / EXT, 0.0f);
        }
    }
    // stage gathered neighbor features
    for (int i = t; i < cnt * DM; i += 256) {
        int e = i >> 6, d = i & 63;
        xj[e][d] = xpre[((size_t)b * N_ + nIdx[e]) * DM + d];
    }
    __syncthreads();

    // s[k][d] = sum_e infl[e][k] * xj[e][d]
#pragma unroll
    for (int p = 0; p < 4; p++) {
        int pair = t + p * 256;
        int k = pair >> 6, d = pair & 63;
        float acc = 0.f;
        for (int e = 0; e < cnt; e++) acc = fmaf(infl[e][k], xj[e][d], acc);
        sS[pair] = acc;
    }
    __syncthreads();

    // feat[d'] = sum_{k,d} s[k][d] * kp_W[k][d][d']  (4-way k-split)
    {
        int dprime = t & 63, ks = t >> 6;
        float acc = 0.f;
        for (int k = ks * 4; k < ks * 4 + 4; k++) {
            const float* kw = kp_W + ((size_t)k * DM) * DM + dprime;
#pragma unroll
            for (int d = 0; d < DM; d++) acc = fmaf(sS[k * DM + d], kw[d * DM], acc);
        }
        featP[ks][dprime] = acc;
    }
    __syncthreads();
    if (t < DM) featP[0][t] = featP[0][t] + featP[1][t] + featP[2][t] + featP[3][t];
    if (t < CIN) xg[t] = x[((size_t)b * N_ + ctr) * CIN + t];
    __syncthreads();

    // out[o] = feat @ W_post + b_post + x[ctr] @ W_sc + b_sc
    {
        const int o = t;
        float acc = b_post[o] + b_sc[o];
#pragma unroll 8
        for (int d = 0; d < DM; d++) acc = fmaf(featP[0][d], W_post[d * COUT + o], acc);
#pragma unroll 8
        for (int c = 0; c < CIN; c++) acc = fmaf(xg[c], W_sc[c * COUT + o], acc);
        out_feat[((size_t)(b * M_ + m)) * COUT + o] = acc;
    }
}

extern "C" void kernel_launch(void* const* d_in, const int* in_sizes, int n_in,
                              void* d_out, int out_size, void* d_ws, size_t ws_size,
                              hipStream_t stream) {
    const float* x      = (const float*)d_in[0];
    const float* pos    = (const float*)d_in[1];
    const float* W_pre  = (const float*)d_in[2];
    const float* b_pre  = (const float*)d_in[3];
    const float* kp_pos = (const float*)d_in[4];
    const float* kp_W   = (const float*)d_in[5];
    const float* W_post = (const float*)d_in[6];
    const float* b_post = (const float*)d_in[7];
    const float* W_sc   = (const float*)d_in[8];
    const float* b_sc   = (const float*)d_in[9];

    float* out_feat = (float*)d_out;
    float* out_pos  = (float*)d_out + (size_t)B_ * M_ * COUT;

    int*   idxs = (int*)d_ws;
    float* xpre = (float*)((char*)d_ws + 64 * 1024);

    fps_kernel<<<B_, 512, 0, stream>>>(pos, idxs, out_pos);
    pre_kernel<<<(B_ * N_) / 16, 256, 0, stream>>>(x, W_pre, b_pre, xpre);
    conv_kernel<<<B_ * M_, 256, 0, stream>>>(pos, x, xpre, idxs, kp_pos, kp_W,
                                             W_post, b_post, W_sc, b_sc, out_feat);
}

// Round 5
// 2274.966 us; speedup vs baseline: 2.6799x; 1.0502x over previous
//
#include <hip/hip_runtime.h>

#define B_    4
#define N_    8192
#define CIN   128
#define COUT  256
#define M_    2048
#define K_    16
#define DM    64
#define MAXNN 64
#define CAP   128
#define R2    0.01f
#define EXT   0.1f

typedef float v2f __attribute__((ext_vector_type(2)));

// Exact-rounded squared distance matching numpy's op order: (dx*dx + dy*dy) + dz*dz
__device__ __forceinline__ float d2_exact(float ax, float ay, float az,
                                          float bx, float by, float bz) {
    float dx = ax - bx, dy = ay - by, dz = az - bz;
    return __fadd_rn(__fadd_rn(__fmul_rn(dx, dx), __fmul_rn(dy, dy)), __fmul_rn(dz, dz));
}

// DPP u64-key max step (key only: 2 regs through the butterfly)
#define DPP_STEP2(CTRL)                                                                   \
    {                                                                                     \
        unsigned tlo = (unsigned)__builtin_amdgcn_update_dpp(0, (int)klo, CTRL, 0xF, 0xF, true); \
        unsigned thi = (unsigned)__builtin_amdgcn_update_dpp(0, (int)khi, CTRL, 0xF, 0xF, true); \
        unsigned long long tk = ((unsigned long long)thi << 32) | tlo;                    \
        unsigned long long ck = ((unsigned long long)khi << 32) | klo;                    \
        if (tk > ck) { klo = tlo; khi = thi; }                                            \
    }

// ---------------- K1 (merged): blocks 0..3 = FPS (one per cloud); blocks >=4 = pre-MLP ----
// FPS: 512 threads (8 waves), 16 pts/lane as 8 x float2 => 64 data VGPRs.
// __launch_bounds__(512,2) grants a 256-VGPR budget so arrays stay in arch VGPRs (no AGPR
// round-trips). Update loop in packed f32 (v_pk_add/mul). Reduction: per-lane best ->
// 6 DPP steps (key u64 = value||~idx; u64 max == numpy argmax with first-index ties) ->
// lane63 ds_max_u64 into a rotating LDS slot -> one barrier -> all read winner, load
// center from global (same-address broadcast). Slot (m+2)&3 zeroed each iter => safe reuse.
__global__ __launch_bounds__(512, 2) void fps_pre_kernel(const float* __restrict__ pos,
                                                         int* __restrict__ idx_out,
                                                         float* __restrict__ out_pos,
                                                         const float* __restrict__ x,
                                                         const float* __restrict__ Wp,
                                                         const float* __restrict__ bvec,
                                                         float* __restrict__ xpre) {
    __shared__ union {
        unsigned long long keySlot[4];
        struct { float Ws[CIN * DM]; float xs[32][CIN]; } p;   // 48 KB
    } sh;

    const int t = threadIdx.x;

    if (blockIdx.x >= 4) {
        // ---------------- pre-MLP branch: 32 rows per block ----------------
        const size_t rowBase = (size_t)(blockIdx.x - 4) * 32;
        for (int i = t; i < CIN * DM; i += 512) sh.p.Ws[i] = Wp[i];
        for (int i = t; i < 32 * CIN; i += 512) {
            int r = i >> 7, c = i & 127;
            sh.p.xs[r][c] = x[(rowBase + r) * CIN + c];
        }
        __syncthreads();
        const int col = t & 63, r0 = t >> 6;   // r0 in [0,8)
        float acc[4];
        float bias = bvec[col];
#pragma unroll
        for (int rr = 0; rr < 4; rr++) acc[rr] = bias;
        for (int c = 0; c < CIN; c++) {
            float w = sh.p.Ws[c * DM + col];
#pragma unroll
            for (int rr = 0; rr < 4; rr++) acc[rr] = fmaf(sh.p.xs[r0 + 8 * rr][c], w, acc[rr]);
        }
#pragma unroll
        for (int rr = 0; rr < 4; rr++) xpre[(rowBase + r0 + 8 * rr) * DM + col] = acc[rr];
        return;
    }

    // ---------------- FPS branch ----------------
    const int b = blockIdx.x;
    const float* pb = pos + (size_t)b * N_ * 3;

    v2f px[8], py[8], pz[8], mind[8];
#pragma unroll
    for (int jj = 0; jj < 8; jj++) {
        int n0 = t + (2 * jj) * 512, n1 = n0 + 512;
        px[jj] = (v2f){pb[n0 * 3 + 0], pb[n1 * 3 + 0]};
        py[jj] = (v2f){pb[n0 * 3 + 1], pb[n1 * 3 + 1]};
        pz[jj] = (v2f){pb[n0 * 3 + 2], pb[n1 * 3 + 2]};
        mind[jj] = (v2f){1e30f, 1e30f};
    }
    float cx = pb[0], cy = pb[1], cz = pb[2];
    if (t < 4) sh.keySlot[t] = 0ull;
    if (t == 0) {
        idx_out[b * M_ + 0] = 0;
        float* op = out_pos + ((size_t)(b * M_ + 0)) * 3;
        op[0] = cx; op[1] = cy; op[2] = cz;
    }
    __syncthreads();

    for (int m = 1; m < M_; m++) {
        // fused mind-update + lane-local argmax over 16 pts (8 packed pairs).
        // Ascending slot order => strict > keeps first max => smallest index on ties.
        float bv = -1.0f; int bj = 0;
        {
#pragma clang fp contract(off)
            v2f cx2 = (v2f){cx, cx}, cy2 = (v2f){cy, cy}, cz2 = (v2f){cz, cz};
#pragma unroll
            for (int jj = 0; jj < 8; jj++) {
                v2f dx = px[jj] - cx2, dy = py[jj] - cy2, dz = pz[jj] - cz2;
                v2f d = (dx * dx + dy * dy) + dz * dz;
                v2f mo = mind[jj];
                float n0 = fminf(mo.x, d.x);
                float n1 = fminf(mo.y, d.y);
                mind[jj] = (v2f){n0, n1};
                if (n0 > bv) { bv = n0; bj = 2 * jj; }
                if (n1 > bv) { bv = n1; bj = 2 * jj + 1; }
            }
        }
        const int bn = t + (bj << 9);
        unsigned klo = ~(unsigned)bn;
        unsigned khi = __float_as_uint(bv);

        // wave64 max-reduce via DPP; winner lands in lane 63
        DPP_STEP2(0x111)  // row_shr:1
        DPP_STEP2(0x112)  // row_shr:2
        DPP_STEP2(0x114)  // row_shr:4
        DPP_STEP2(0x118)  // row_shr:8
        DPP_STEP2(0x142)  // row_bcast:15
        DPP_STEP2(0x143)  // row_bcast:31

        const int buf = m & 3;
        if ((t & 63) == 63) {
            atomicMax(&sh.keySlot[buf], ((unsigned long long)khi << 32) | klo);
        }
        __syncthreads();
        const unsigned long long k0 = sh.keySlot[buf];
        if (t == 0) sh.keySlot[(m + 2) & 3] = 0ull;   // reuse-safe: >=1 barrier away
        const unsigned widx = ~(unsigned)(k0 & 0xFFFFFFFFull);
        const float* cp = pb + (size_t)widx * 3;
        cx = cp[0]; cy = cp[1]; cz = cp[2];
        if (t == 0) {
            idx_out[b * M_ + m] = (int)widx;
            float* op = out_pos + ((size_t)(b * M_ + m)) * 3;
            op[0] = cx; op[1] = cy; op[2] = cz;
        }
    }
}

// ---------------- K3: fused neighbor search + KPConv + post + shortcut ----------------
__global__ __launch_bounds__(256) void conv_kernel(const float* __restrict__ pos,
                                                   const float* __restrict__ x,
                                                   const float* __restrict__ xpre,
                                                   const int* __restrict__ idxs,
                                                   const float* __restrict__ kp_pos,
                                                   const float* __restrict__ kp_W,
                                                   const float* __restrict__ W_post,
                                                   const float* __restrict__ b_post,
                                                   const float* __restrict__ W_sc,
                                                   const float* __restrict__ b_sc,
                                                   float* __restrict__ out_feat) {
    const int blk = blockIdx.x;
    const int b = blk / M_;
    const int m = blk % M_;
    const int t = threadIdx.x;

    __shared__ int   nIdx[CAP];
    __shared__ float nD2[CAP];
    __shared__ int   cntS;
    __shared__ float infl[MAXNN][K_];   // 4 KB
    __shared__ float xj[MAXNN][DM];     // 16 KB
    __shared__ float sS[K_ * DM];       // 4 KB
    __shared__ float featP[4][DM];      // 1 KB
    __shared__ float xg[CIN];           // 0.5 KB

    const float* pb = pos + (size_t)b * N_ * 3;
    const int ctr = idxs[b * M_ + m];
    const float cx = pb[ctr * 3 + 0], cy = pb[ctr * 3 + 1], cz = pb[ctr * 3 + 2];

    if (t == 0) cntS = 0;
    __syncthreads();

    // neighbor scan over all N points
    for (int j = 0; j < N_ / 256; j++) {
        int n = j * 256 + t;
        float x0 = pb[n * 3 + 0], y0 = pb[n * 3 + 1], z0 = pb[n * 3 + 2];
        float d = d2_exact(x0, y0, z0, cx, cy, cz);
        if (d <= R2) {
            int p = atomicAdd(&cntS, 1);
            if (p < CAP) { nIdx[p] = n; nD2[p] = d; }
        }
    }
    __syncthreads();
    int cnt = cntS; if (cnt > CAP) cnt = CAP;
    if (cnt > MAXNN) {
        // rare path: keep the 64 lexicographically-smallest (d2, idx) = stable top_k
        if (t == 0) {
            for (int s = 0; s < MAXNN; s++) {
                int best = s;
                for (int q = s + 1; q < cnt; q++) {
                    if (nD2[q] < nD2[best] || (nD2[q] == nD2[best] && nIdx[q] < nIdx[best])) best = q;
                }
                float td = nD2[best]; nD2[best] = nD2[s]; nD2[s] = td;
                int ti = nIdx[best]; nIdx[best] = nIdx[s]; nIdx[s] = ti;
            }
        }
        __syncthreads();
        cnt = MAXNN;
    }

    // influence weights (one thread per neighbor)
    if (t < cnt) {
        int n = nIdx[t];
        float rx = pb[n * 3 + 0] - cx, ry = pb[n * 3 + 1] - cy, rz = pb[n * 3 + 2] - cz;
#pragma unroll
        for (int k = 0; k < K_; k++) {
            float dx = rx - kp_pos[k * 3 + 0];
            float dy = ry - kp_pos[k * 3 + 1];
            float dz = rz - kp_pos[k * 3 + 2];
            float dist = sqrtf(dx * dx + dy * dy + dz * dz + 1e-12f);
            infl[t][k] = fmaxf(1.0f - dist / EXT, 0.0f);
        }
    }
    // stage gathered neighbor features
    for (int i = t; i < cnt * DM; i += 256) {
        int e = i >> 6, d = i & 63;
        xj[e][d] = xpre[((size_t)b * N_ + nIdx[e]) * DM + d];
    }
    __syncthreads();

    // s[k][d] = sum_e infl[e][k] * xj[e][d]
#pragma unroll
    for (int p = 0; p < 4; p++) {
        int pair = t + p * 256;
        int k = pair >> 6, d = pair & 63;
        float acc = 0.f;
        for (int e = 0; e < cnt; e++) acc = fmaf(infl[e][k], xj[e][d], acc);
        sS[pair] = acc;
    }
    __syncthreads();

    // feat[d'] = sum_{k,d} s[k][d] * kp_W[k][d][d']  (4-way k-split)
    {
        int dprime = t & 63, ks = t >> 6;
        float acc = 0.f;
        for (int k = ks * 4; k < ks * 4 + 4; k++) {
            const float* kw = kp_W + ((size_t)k * DM) * DM + dprime;
#pragma unroll
            for (int d = 0; d < DM; d++) acc = fmaf(sS[k * DM + d], kw[d * DM], acc);
        }
        featP[ks][dprime] = acc;
    }
    __syncthreads();
    if (t < DM) featP[0][t] = featP[0][t] + featP[1][t] + featP[2][t] + featP[3][t];
    if (t < CIN) xg[t] = x[((size_t)b * N_ + ctr) * CIN + t];
    __syncthreads();

    // out[o] = feat @ W_post + b_post + x[ctr] @ W_sc + b_sc
    {
        const int o = t;
        float acc = b_post[o] + b_sc[o];
#pragma unroll 8
        for (int d = 0; d < DM; d++) acc = fmaf(featP[0][d], W_post[d * COUT + o], acc);
#pragma unroll 8
        for (int c = 0; c < CIN; c++) acc = fmaf(xg[c], W_sc[c * COUT + o], acc);
        out_feat[((size_t)(b * M_ + m)) * COUT + o] = acc;
    }
}

extern "C" void kernel_launch(void* const* d_in, const int* in_sizes, int n_in,
                              void* d_out, int out_size, void* d_ws, size_t ws_size,
                              hipStream_t stream) {
    const float* x      = (const float*)d_in[0];
    const float* pos    = (const float*)d_in[1];
    const float* W_pre  = (const float*)d_in[2];
    const float* b_pre  = (const float*)d_in[3];
    const float* kp_pos = (const float*)d_in[4];
    const float* kp_W   = (const float*)d_in[5];
    const float* W_post = (const float*)d_in[6];
    const float* b_post = (const float*)d_in[7];
    const float* W_sc   = (const float*)d_in[8];
    const float* b_sc   = (const float*)d_in[9];

    float* out_feat = (float*)d_out;
    float* out_pos  = (float*)d_out + (size_t)B_ * M_ * COUT;

    int*   idxs = (int*)d_ws;
    float* xpre = (float*)((char*)d_ws + 64 * 1024);

    fps_pre_kernel<<<4 + (B_ * N_) / 32, 512, 0, stream>>>(pos, idxs, out_pos,
                                                           x, W_pre, b_pre, xpre);
    conv_kernel<<<B_ * M_, 256, 0, stream>>>(pos, x, xpre, idxs, kp_pos, kp_W,
                                             W_post, b_post, W_sc, b_sc, out_feat);
}